// Round 1
// baseline (797.089 us; speedup 1.0000x reference)
//
#include <hip/hip_runtime.h>

#define NSEQ 32768
#define NB 8
#define NC 16

__device__ __forceinline__ float sigm_f(float x) {
    return __fdividef(1.f, 1.f + __expf(-x));
}
__device__ __forceinline__ float tanh_f(float x) {
    return __fdividef(2.f, 1.f + __expf(-2.f * x)) - 1.f;
}

// Layer 0: h = xin + causal_conv(xin, w0, b0, d=1), xin = x/32768
__global__ __launch_bounds__(256) void k_layer0(
    const float* __restrict__ x, const float* __restrict__ w0,
    const float* __restrict__ b0, float* __restrict__ h)
{
    int tid = blockIdx.x * 256 + threadIdx.x;      // position index over B*N
    int n = tid & (NSEQ - 1);
    const float inv = 1.f / 32768.f;
    float xc = x[tid] * inv;
    float xp = (n >= 1) ? x[tid - 1] * inv : 0.f;
    float v[NC];
#pragma unroll
    for (int c = 0; c < NC; c++) {
        float o = w0[c * 2] * xp + w0[c * 2 + 1] * xc + b0[c];
        v[c] = xc + o;
    }
    float4* ph = (float4*)(h + (size_t)tid * NC);
#pragma unroll
    for (int i = 0; i < 4; i++)
        ph[i] = make_float4(v[i * 4], v[i * 4 + 1], v[i * 4 + 2], v[i * 4 + 3]);
}

// Gated layer i: h_out = h_in + tanh(f)*sigmoid(g), f/g = causal convs of h_in
__global__ __launch_bounds__(256) void k_layer(
    const float* __restrict__ hin, float* __restrict__ hout,
    const float* __restrict__ wf, const float* __restrict__ bf,
    const float* __restrict__ wg, const float* __restrict__ bg, int d)
{
    int tid = blockIdx.x * 256 + threadIdx.x;
    int n = tid & (NSEQ - 1);

    float hc[NC], hp[NC];
    {
        const float4* pc = (const float4*)(hin + (size_t)tid * NC);
#pragma unroll
        for (int i = 0; i < 4; i++) {
            float4 t = pc[i];
            hc[i * 4] = t.x; hc[i * 4 + 1] = t.y; hc[i * 4 + 2] = t.z; hc[i * 4 + 3] = t.w;
        }
    }
    if (n >= d) {
        const float4* pp = (const float4*)(hin + (size_t)(tid - d) * NC);
#pragma unroll
        for (int i = 0; i < 4; i++) {
            float4 t = pp[i];
            hp[i * 4] = t.x; hp[i * 4 + 1] = t.y; hp[i * 4 + 2] = t.z; hp[i * 4 + 3] = t.w;
        }
    } else {
#pragma unroll
        for (int i = 0; i < NC; i++) hp[i] = 0.f;
    }

    float f[NC], g[NC];
#pragma unroll
    for (int co = 0; co < NC; co++) { f[co] = bf[co]; g[co] = bg[co]; }

#pragma unroll
    for (int ci = 0; ci < NC; ci++) {
        float xp = hp[ci], xc = hc[ci];
#pragma unroll
        for (int co = 0; co < NC; co++) {
            // weights are wave-uniform -> scalar loads, 1 SGPR operand per v_fma
            f[co] = fmaf(wf[(co * NC + ci) * 2 + 0], xp, f[co]);
            f[co] = fmaf(wf[(co * NC + ci) * 2 + 1], xc, f[co]);
            g[co] = fmaf(wg[(co * NC + ci) * 2 + 0], xp, g[co]);
            g[co] = fmaf(wg[(co * NC + ci) * 2 + 1], xc, g[co]);
        }
    }

    float v[NC];
#pragma unroll
    for (int co = 0; co < NC; co++) {
        float outv = tanh_f(f[co]) * sigm_f(g[co]);
        v[co] = hc[co] + outv;
    }
    float4* po = (float4*)(hout + (size_t)tid * NC);
#pragma unroll
    for (int i = 0; i < 4; i++)
        po[i] = make_float4(v[i * 4], v[i * 4 + 1], v[i * 4 + 2], v[i * 4 + 3]);
}

// Head: agg = h_final - xin; a = relu(wa@relu(agg)+ba); o = wo@a+bo;
// log_softmax over 256 channels; mask by lengths. 64 positions per block.
__global__ __launch_bounds__(256) void k_final(
    const float* __restrict__ hfin, const float* __restrict__ x,
    const int* __restrict__ lengths,
    const float* __restrict__ wa, const float* __restrict__ ba,
    const float* __restrict__ wo, const float* __restrict__ bo,
    float* __restrict__ out)
{
    __shared__ float s_r[64][17];    // relu(agg), odd stride: conflict-free
    __shared__ float s_ra[64][65];   // relu(a)
    __shared__ float s_red[2][4][64];

    int t = threadIdx.x;
    int p = t & 63;
    int q = __builtin_amdgcn_readfirstlane(t >> 6);   // wave index, scalar
    int blk = blockIdx.x;
    int b = blk >> 9;                 // 512 tiles of 64 per batch
    int n0 = (blk & 511) << 6;
    int n = n0 + p;
    size_t pos = (size_t)b * NSEQ + n;
    float xin = x[pos] * (1.f / 32768.f);

    // phase 1: stage relu(h - xin)
    {
        const float4* ph = (const float4*)(hfin + pos * NC);
        float4 v = ph[q];
        s_r[p][q * 4 + 0] = fmaxf(v.x - xin, 0.f);
        s_r[p][q * 4 + 1] = fmaxf(v.y - xin, 0.f);
        s_r[p][q * 4 + 2] = fmaxf(v.z - xin, 0.f);
        s_r[p][q * 4 + 3] = fmaxf(v.w - xin, 0.f);
    }
    __syncthreads();

    // phase 2: a[j] for j = q*16 .. q*16+15
    {
        float r[NC];
#pragma unroll
        for (int c = 0; c < NC; c++) r[c] = s_r[p][c];
#pragma unroll
        for (int jj = 0; jj < 16; jj++) {
            int j = q * 16 + jj;
            float acc = ba[j];
#pragma unroll
            for (int c = 0; c < NC; c++) acc = fmaf(wa[j * NC + c], r[c], acc);
            s_ra[p][j] = fmaxf(acc, 0.f);
        }
    }
    __syncthreads();

    // phase 3: o[k] for k = q*64 .. q*64+63, logsumexp across block
    float ra[64];
#pragma unroll
    for (int j = 0; j < 64; j++) ra[j] = s_ra[p][j];

    float o[64];
    float m = -1e30f;
#pragma unroll 8
    for (int kk = 0; kk < 64; kk++) {
        int k = q * 64 + kk;
        float acc = bo[k];
#pragma unroll
        for (int j = 0; j < 64; j++) acc = fmaf(wo[k * 64 + j], ra[j], acc);
        o[kk] = acc;
        m = fmaxf(m, acc);
    }
    s_red[0][q][p] = m;
    __syncthreads();
    m = fmaxf(fmaxf(s_red[0][0][p], s_red[0][1][p]),
              fmaxf(s_red[0][2][p], s_red[0][3][p]));
    float s = 0.f;
#pragma unroll
    for (int kk = 0; kk < 64; kk++) s += __expf(o[kk] - m);
    s_red[1][q][p] = s;
    __syncthreads();
    s = s_red[1][0][p] + s_red[1][1][p] + s_red[1][2][p] + s_red[1][3][p];
    float lse = m + __logf(s);

    bool valid = n < lengths[b];
    float* po = out + ((size_t)b * 256 + q * 64) * NSEQ + n;
#pragma unroll
    for (int kk = 0; kk < 64; kk++) {
        po[(size_t)kk * NSEQ] = valid ? (o[kk] - lse) : 0.f;
    }
}

extern "C" void kernel_launch(void* const* d_in, const int* in_sizes, int n_in,
                              void* d_out, int out_size, void* d_ws, size_t ws_size,
                              hipStream_t stream) {
    const float* x   = (const float*)d_in[0];
    const int* lens  = (const int*)d_in[1];
    const float* w0  = (const float*)d_in[2];
    const float* b0  = (const float*)d_in[3];
    const float* wf  = (const float*)d_in[4];
    const float* bf  = (const float*)d_in[5];
    const float* wg  = (const float*)d_in[6];
    const float* bg  = (const float*)d_in[7];
    const float* wa  = (const float*)d_in[8];
    const float* ba  = (const float*)d_in[9];
    const float* wo  = (const float*)d_in[10];
    const float* bo  = (const float*)d_in[11];
    float* out = (float*)d_out;

    float* hA = (float*)d_ws;                          // [B][N][16]
    float* hB = hA + (size_t)NB * NSEQ * NC;           // ping-pong (32 MiB total)

    const int total = NB * NSEQ;
    dim3 blk(256);
    dim3 grd(total / 256);

    k_layer0<<<grd, blk, 0, stream>>>(x, w0, b0, hA);

    float* cur = hA;
    float* nxt = hB;
    for (int i = 1; i <= 29; i++) {
        int d = 1 << (i % 10);
        k_layer<<<grd, blk, 0, stream>>>(cur, nxt,
                                         wf + (size_t)(i - 1) * NC * NC * 2,
                                         bf + (size_t)(i - 1) * NC,
                                         wg + (size_t)(i - 1) * NC * NC * 2,
                                         bg + (size_t)(i - 1) * NC, d);
        float* tmp = cur; cur = nxt; nxt = tmp;
    }

    dim3 fgrd(NB * (NSEQ / 64));
    k_final<<<fgrd, blk, 0, stream>>>(cur, x, lens, wa, ba, wo, bo, out);
}